// Round 1
// baseline (380.678 us; speedup 1.0000x reference)
//
#include <hip/hip_runtime.h>

#define TT 16   // NUM_TYPES
#define DD 128  // OUT_DIM

// Kernel A: p = softmax(relu(r@W1+b1) @ Wp + bp), one thread per node.
// No z[128] array: accumulate logits on the fly (keeps VGPR low).
__global__ __launch_bounds__(256) void k_node_mlp(
    const float* __restrict__ r, const float* __restrict__ W1,
    const float* __restrict__ b1, const float* __restrict__ Wp,
    const float* __restrict__ bp, float* __restrict__ p, int n_nodes)
{
    __shared__ float sW1[TT * DD];   // [16][128]
    __shared__ float sWp[DD * TT];   // [128][16]
    __shared__ float sb1[DD];
    __shared__ float sbp[TT];
    for (int i = threadIdx.x; i < TT * DD; i += 256) { sW1[i] = W1[i]; sWp[i] = Wp[i]; }
    if (threadIdx.x < DD) sb1[threadIdx.x] = b1[threadIdx.x];
    if (threadIdx.x < TT) sbp[threadIdx.x] = bp[threadIdx.x];
    __syncthreads();

    int n = blockIdx.x * 256 + threadIdx.x;
    if (n >= n_nodes) return;

    const float4* rp = (const float4*)(r + (size_t)n * TT);
    float4 r0 = rp[0], r1 = rp[1], r2 = rp[2], r3 = rp[3];
    float rv[TT] = {r0.x, r0.y, r0.z, r0.w, r1.x, r1.y, r1.z, r1.w,
                    r2.x, r2.y, r2.z, r2.w, r3.x, r3.y, r3.z, r3.w};

    float logit[TT];
#pragma unroll
    for (int t = 0; t < TT; ++t) logit[t] = sbp[t];

    for (int j = 0; j < DD; j += 4) {
        float4 z = *(const float4*)(&sb1[j]);
#pragma unroll
        for (int k = 0; k < TT; ++k) {
            float4 w = *(const float4*)(&sW1[k * DD + j]);
            z.x = fmaf(rv[k], w.x, z.x);
            z.y = fmaf(rv[k], w.y, z.y);
            z.z = fmaf(rv[k], w.z, z.z);
            z.w = fmaf(rv[k], w.w, z.w);
        }
        z.x = fmaxf(z.x, 0.f); z.y = fmaxf(z.y, 0.f);
        z.z = fmaxf(z.z, 0.f); z.w = fmaxf(z.w, 0.f);
#pragma unroll
        for (int t4 = 0; t4 < TT; t4 += 4) {
            float4 w0 = *(const float4*)(&sWp[(j + 0) * TT + t4]);
            float4 w1 = *(const float4*)(&sWp[(j + 1) * TT + t4]);
            float4 w2 = *(const float4*)(&sWp[(j + 2) * TT + t4]);
            float4 w3 = *(const float4*)(&sWp[(j + 3) * TT + t4]);
            logit[t4 + 0] += z.x * w0.x + z.y * w1.x + z.z * w2.x + z.w * w3.x;
            logit[t4 + 1] += z.x * w0.y + z.y * w1.y + z.z * w2.y + z.w * w3.y;
            logit[t4 + 2] += z.x * w0.z + z.y * w1.z + z.z * w2.z + z.w * w3.z;
            logit[t4 + 3] += z.x * w0.w + z.y * w1.w + z.z * w2.w + z.w * w3.w;
        }
    }

    // softmax over 16
    float m = logit[0];
#pragma unroll
    for (int t = 1; t < TT; ++t) m = fmaxf(m, logit[t]);
    float e[TT];
    float s = 0.f;
#pragma unroll
    for (int t = 0; t < TT; ++t) { e[t] = expf(logit[t] - m); s += e[t]; }
    float inv = 1.f / s;

    float4* pp = (float4*)(p + (size_t)n * TT);
    pp[0] = make_float4(e[0] * inv, e[1] * inv, e[2] * inv, e[3] * inv);
    pp[1] = make_float4(e[4] * inv, e[5] * inv, e[6] * inv, e[7] * inv);
    pp[2] = make_float4(e[8] * inv, e[9] * inv, e[10] * inv, e[11] * inv);
    pp[3] = make_float4(e[12] * inv, e[13] * inv, e[14] * inv, e[15] * inv);
}

// Kernel B: scatter-add.  16 threads per edge: thread (e,t) does
// msum[dst[e]][t] += p[src[e]][t];  lane t==0 also counts degree.
__global__ __launch_bounds__(256) void k_scatter(
    const int* __restrict__ src, const int* __restrict__ dst,
    const float* __restrict__ p, float* __restrict__ msum,
    float* __restrict__ deg, int n_edges)
{
    long long gid = (long long)blockIdx.x * 256 + threadIdx.x;
    int e = (int)(gid >> 4);
    int t = (int)(gid & 15);
    if (e >= n_edges) return;
    int s = src[e];
    int d = dst[e];
    float v = p[(size_t)s * TT + t];
    atomicAdd(&msum[(size_t)d * TT + t], v);
    if (t == 0) atomicAdd(&deg[d], 1.0f);
}

// Kernel C: out = relu((msum/max(deg,1)) @ Wf + bf).  32 threads per node,
// each thread produces 4 consecutive outputs (coalesced float4 store).
__global__ __launch_bounds__(256) void k_final(
    const float* __restrict__ msum, const float* __restrict__ deg,
    const float* __restrict__ Wf, const float* __restrict__ bf,
    float* __restrict__ out, int n_nodes)
{
    __shared__ float sWf[TT * DD];   // [16][128]
    __shared__ float sbf[DD];
    for (int i = threadIdx.x; i < TT * DD; i += 256) sWf[i] = Wf[i];
    if (threadIdx.x < DD) sbf[threadIdx.x] = bf[threadIdx.x];
    __syncthreads();

    long long gid = (long long)blockIdx.x * 256 + threadIdx.x;
    int n = (int)(gid >> 5);
    int j = (int)(gid & 31) * 4;
    if (n >= n_nodes) return;

    float invd = 1.0f / fmaxf(deg[n], 1.0f);
    float4 acc = *(const float4*)(&sbf[j]);
#pragma unroll
    for (int t = 0; t < TT; ++t) {
        float nd = msum[(size_t)n * TT + t] * invd;
        float4 w = *(const float4*)(&sWf[t * DD + j]);
        acc.x = fmaf(nd, w.x, acc.x);
        acc.y = fmaf(nd, w.y, acc.y);
        acc.z = fmaf(nd, w.z, acc.z);
        acc.w = fmaf(nd, w.w, acc.w);
    }
    acc.x = fmaxf(acc.x, 0.f); acc.y = fmaxf(acc.y, 0.f);
    acc.z = fmaxf(acc.z, 0.f); acc.w = fmaxf(acc.w, 0.f);
    *(float4*)(&out[(size_t)n * DD + j]) = acc;
}

extern "C" void kernel_launch(void* const* d_in, const int* in_sizes, int n_in,
                              void* d_out, int out_size, void* d_ws, size_t ws_size,
                              hipStream_t stream) {
    const float* r  = (const float*)d_in[0];
    const int*   src = (const int*)d_in[1];
    const int*   dst = (const int*)d_in[2];
    const float* W1 = (const float*)d_in[3];
    const float* b1 = (const float*)d_in[4];
    const float* Wp = (const float*)d_in[5];
    const float* bp = (const float*)d_in[6];
    const float* Wf = (const float*)d_in[7];
    const float* bf = (const float*)d_in[8];
    float* out = (float*)d_out;

    int n_nodes = in_sizes[0] / TT;
    int n_edges = in_sizes[1];

    char* ws = (char*)d_ws;
    float* p    = (float*)ws;                                   // N*16 f32
    float* msum = (float*)(ws + (size_t)n_nodes * TT * 4);      // N*16 f32
    float* deg  = (float*)(ws + (size_t)n_nodes * TT * 4 * 2);  // N f32
    // zero msum + deg (contiguous)
    hipMemsetAsync(msum, 0, (size_t)n_nodes * TT * 4 + (size_t)n_nodes * 4, stream);

    int blocksA = (n_nodes + 255) / 256;
    k_node_mlp<<<blocksA, 256, 0, stream>>>(r, W1, b1, Wp, bp, p, n_nodes);

    long long tot = (long long)n_edges * TT;
    int blocksB = (int)((tot + 255) / 256);
    k_scatter<<<blocksB, 256, 0, stream>>>(src, dst, p, msum, deg, n_edges);

    long long totC = (long long)n_nodes * 32;
    int blocksC = (int)((totC + 255) / 256);
    k_final<<<blocksC, 256, 0, stream>>>(msum, deg, Wf, bf, out, n_nodes);
}